// Round 3
// baseline (473.589 us; speedup 1.0000x reference)
//
#include <hip/hip_runtime.h>
#include <hip/hip_bf16.h>

// SparseGAT forward. fp16-MFMA feature transform; CSR-fused edge pipeline.
// N=50000, FI=256, FO=64, H=8, E=800000.
//
// ws layout: Th[N*512]f16 | xh[N*256]f16 | Wth[8*64*256]f16 | aw[N*8]f32
//            | deg[N] | row_start[N+4] | cursor[N] | colperm[E]

#define FI 256
#define FO 64
#define NH 8
#define FC (NH * FO)  // 512

typedef _Float16 f16x8 __attribute__((ext_vector_type(8)));
typedef float f32x16 __attribute__((ext_vector_type(16)));
typedef float f32x8 __attribute__((ext_vector_type(8)));

// ---------------- P0: x fp32 -> fp16 ----------------------------------------
__global__ __launch_bounds__(256)
void p0_xconv(const float* __restrict__ x, _Float16* __restrict__ xh, int total4) {
  int i = blockIdx.x * 256 + threadIdx.x;
  if (i >= total4) return;
  float4 v = reinterpret_cast<const float4*>(x)[i];
  _Float16 o[4] = {(_Float16)v.x, (_Float16)v.y, (_Float16)v.z, (_Float16)v.w};
  *reinterpret_cast<uint2*>(&xh[(size_t)i * 4]) = *reinterpret_cast<uint2*>(o);
}

// ---------------- P1: W[h][k][f] -> Wth[h][f][k] fp16 -----------------------
__global__ __launch_bounds__(256)
void p1_wconv(const float* __restrict__ W, _Float16* __restrict__ Wth) {
  int idx = blockIdx.x * 256 + threadIdx.x;   // h*64*256 + f*256 + k
  if (idx >= NH * FO * FI) return;
  int k = idx & (FI - 1);
  int f = (idx >> 8) & (FO - 1);
  int h = idx >> 14;
  Wth[idx] = (_Float16)W[((size_t)h * FI + k) * FO + f];
}

// ---------------- K1: T = x @ W per head, fp16 MFMA -------------------------
__global__ __launch_bounds__(256)
void k1_mfma(const _Float16* __restrict__ xh, const _Float16* __restrict__ Wth,
             _Float16* __restrict__ Th, int N) {
  __shared__ _Float16 Xs[64][264];
  const int h   = blockIdx.y;
  const int bm  = blockIdx.x * 64;
  const int t   = threadIdx.x;
  const int lane = t & 63;
  const int wid  = t >> 6;
  const int wr = wid >> 1, wc = wid & 1;

  #pragma unroll
  for (int r = 0; r < 8; ++r) {
    int i = t + r * 256;
    int row = i >> 5;
    int c8 = (i & 31) * 8;
    int grow = bm + row;
    f16x8 v = {};
    if (grow < N)
      v = *reinterpret_cast<const f16x8*>(&xh[(size_t)grow * FI + c8]);
    *reinterpret_cast<f16x8*>(&Xs[row][c8]) = v;
  }
  __syncthreads();

  const int l31 = lane & 31;
  const int kh  = (lane >> 5) * 8;
  const _Float16* Wcol = Wth + ((size_t)h * FO + wc * 32 + l31) * FI;
  const int arow = wr * 32 + l31;

  f32x16 acc = (f32x16)0.0f;
  #pragma unroll
  for (int kk = 0; kk < 16; ++kk) {
    f16x8 af = *reinterpret_cast<const f16x8*>(&Xs[arow][kk * 16 + kh]);
    f16x8 bf = *reinterpret_cast<const f16x8*>(&Wcol[kk * 16 + kh]);
    acc = __builtin_amdgcn_mfma_f32_32x32x16_f16(af, bf, acc, 0, 0, 0);
  }

  const int cbase = h * FO + wc * 32 + l31;
  #pragma unroll
  for (int reg = 0; reg < 16; ++reg) {
    int rr = (reg & 3) + 8 * (reg >> 2) + 4 * (lane >> 5);
    int grow = bm + wr * 32 + rr;
    if (grow < N) Th[(size_t)grow * FC + cbase] = (_Float16)acc[reg];
  }
}

// ---------------- K2: aw[n,h] = dot(T[n,h*64:], a[h]) -----------------------
__global__ __launch_bounds__(512)
void k2_aw(const _Float16* __restrict__ Th, const float* __restrict__ a,
           float* __restrict__ aw, int N) {
  int n = blockIdx.x;
  int w = threadIdx.x >> 6;
  int lane = threadIdx.x & 63;
  float v = (float)Th[(size_t)n * FC + w * FO + lane] * a[w * FO + lane];
  #pragma unroll
  for (int off = 32; off; off >>= 1) v += __shfl_down(v, off);
  if (lane == 0) aw[n * NH + w] = v;
}

// ---------------- B1: degree histogram --------------------------------------
__global__ __launch_bounds__(256)
void b1_hist(const int* __restrict__ rows, int* __restrict__ deg, int E) {
  int e = blockIdx.x * 256 + threadIdx.x;
  if (e < E) atomicAdd(&deg[rows[e]], 1);
}

// ---------------- B2: single-block exclusive scan -> row_start, cursor ------
__global__ __launch_bounds__(1024)
void b2_scan(const int* __restrict__ deg, int* __restrict__ row_start,
             int* __restrict__ cursor, int N) {
  __shared__ int sums[1024];
  const int t = threadIdx.x;
  const int PER = (N + 1023) / 1024;
  const int base = t * PER;
  int s = 0;
  for (int j = 0; j < PER; ++j)
    if (base + j < N) s += deg[base + j];
  sums[t] = s;
  __syncthreads();
  for (int off = 1; off < 1024; off <<= 1) {
    int add = (t >= off) ? sums[t - off] : 0;
    __syncthreads();
    sums[t] += add;
    __syncthreads();
  }
  int run = sums[t] - s;   // exclusive prefix of thread-chunk
  for (int j = 0; j < PER; ++j) {
    int i = base + j;
    if (i < N) {
      row_start[i] = run;
      cursor[i]    = run;
      run += deg[i];
    }
  }
  if (t == 1023) row_start[N] = run;
}

// ---------------- B3: scatter cols into CSR order ---------------------------
__global__ __launch_bounds__(256)
void b3_scatter(const int* __restrict__ rows, const int* __restrict__ cols,
                int* __restrict__ cursor, int* __restrict__ colperm, int E) {
  int e = blockIdx.x * 256 + threadIdx.x;
  if (e >= E) return;
  int pos = atomicAdd(&cursor[rows[e]], 1);
  colperm[pos] = cols[e];
}

// ---------------- K4: fused softmax + aggregation + bias + relu -------------
// one wave per row; edges lane-parallel for ex/den, serial for feature gather.
__global__ __launch_bounds__(256)
void k4_fused(const int* __restrict__ row_start, const int* __restrict__ colperm,
              const float* __restrict__ aw, const _Float16* __restrict__ Th,
              const float* __restrict__ b, float* __restrict__ out, int N) {
  const int lane = threadIdx.x & 63;
  const int r = blockIdx.x * 4 + (threadIdx.x >> 6);
  if (r >= N) return;

  const int s0 = row_start[r], s1 = row_start[r + 1];

  f32x8 awr = *reinterpret_cast<const f32x8*>(&aw[(size_t)r * NH]);

  float facc[NH] = {};
  float dacc[NH] = {};

  for (int base = s0; base < s1; base += 64) {
    const int m = min(64, s1 - base);
    const bool valid = lane < m;
    int c_l = valid ? colperm[base + lane] : 0;

    // (a) lane-parallel: ex for this lane's edge
    f32x8 awc = *reinterpret_cast<const f32x8*>(&aw[(size_t)c_l * NH]);
    float ex[NH];
    #pragma unroll
    for (int h = 0; h < NH; ++h) {
      float s = awr[h] + awc[h];
      float lr = s > 0.f ? s : 0.2f * s;
      ex[h] = valid ? __expf(lr) : 0.f;
      dacc[h] += ex[h];
    }

    // (b) serial over edges: gather T[c] row, accumulate unnormalized
    for (int j = 0; j < m; ++j) {
      int cj = __shfl(c_l, j);
      const _Float16* tp = Th + (size_t)cj * FC + lane;
      #pragma unroll
      for (int h = 0; h < NH; ++h) {
        float e_jh = __shfl(ex[h], j);
        facc[h] = fmaf(e_jh, (float)tp[h * FO], facc[h]);
      }
    }
  }

  // reduce den across lanes
  #pragma unroll
  for (int h = 0; h < NH; ++h) {
    #pragma unroll
    for (int off = 1; off < 64; off <<= 1)
      dacc[h] += __shfl_xor(dacc[h], off);
  }

  float sb = 0.f;
  #pragma unroll
  for (int h = 0; h < NH; ++h) sb += b[h * FO + lane];

  float v = 0.f;
  #pragma unroll
  for (int h = 0; h < NH; ++h) {
    float rden = dacc[h] > 0.f ? 1.0f / dacc[h] : 0.f;
    v += facc[h] * rden;
  }
  v = (v + sb) * 0.125f;
  out[(size_t)r * FO + lane] = v > 0.f ? v : 0.f;
}

extern "C" void kernel_launch(void* const* d_in, const int* in_sizes, int n_in,
                              void* d_out, int out_size, void* d_ws, size_t ws_size,
                              hipStream_t stream) {
  const float* x    = (const float*)d_in[0];
  const float* W    = (const float*)d_in[1];
  const float* a    = (const float*)d_in[2];
  const float* b    = (const float*)d_in[3];
  const int*   rows = (const int*)d_in[4];
  const int*   cols = (const int*)d_in[5];
  const int N = in_sizes[0] / FI;
  const int E = in_sizes[4];

  char* p = (char*)d_ws;
  _Float16* Th       = (_Float16*)p;  p += (size_t)N * FC * sizeof(_Float16);
  _Float16* xh       = (_Float16*)p;  p += (size_t)N * FI * sizeof(_Float16);
  _Float16* Wth      = (_Float16*)p;  p += (size_t)NH * FO * FI * sizeof(_Float16);
  float*    aw       = (float*)p;     p += (size_t)N * NH * sizeof(float);
  int*      deg      = (int*)p;       p += (size_t)N * sizeof(int);
  int*      row_start= (int*)p;       p += (size_t)(N + 4) * sizeof(int);
  int*      cursor   = (int*)p;       p += (size_t)N * sizeof(int);
  int*      colperm  = (int*)p;       p += (size_t)E * sizeof(int);
  float*    out = (float*)d_out;

  // CSR build
  hipMemsetAsync(deg, 0, (size_t)N * sizeof(int), stream);
  b1_hist<<<(E + 255) / 256, 256, 0, stream>>>(rows, deg, E);
  b2_scan<<<1, 1024, 0, stream>>>(deg, row_start, cursor, N);
  b3_scatter<<<(E + 255) / 256, 256, 0, stream>>>(rows, cols, cursor, colperm, E);

  // dense feature transform
  int total4 = N * FI / 4;
  p0_xconv<<<(total4 + 255) / 256, 256, 0, stream>>>(x, xh, total4);
  p1_wconv<<<(NH * FO * FI + 255) / 256, 256, 0, stream>>>(W, Wth);
  k1_mfma<<<dim3((N + 63) / 64, NH), 256, 0, stream>>>(xh, Wth, Th, N);
  k2_aw<<<N, 512, 0, stream>>>(Th, a, aw, N);

  // fused edge pipeline
  k4_fused<<<(N + 3) / 4, 256, 0, stream>>>(row_start, colperm, aw, Th, b, out, N);
}

// Round 4
// 356.837 us; speedup vs baseline: 1.3272x; 1.3272x over previous
//
#include <hip/hip_runtime.h>
#include <hip/hip_bf16.h>

// SparseGAT forward. fp16-MFMA feature transform; CSR-fused edge pipeline.
// N=50000, FI=256, FO=64, H=8, E=800000.
//
// ws: Th[N*512]f16 | xh[N*256]f16 | Wth[8*64*256]f16 | aw[N*8]f32
//     | deg[N] | row_start[N+4] | cursor[N] | colperm[E] | blocksums[64]

#define FI 256
#define FO 64
#define NH 8
#define FC (NH * FO)  // 512

typedef _Float16 f16x8 __attribute__((ext_vector_type(8)));
typedef float f32x16 __attribute__((ext_vector_type(16)));
typedef float f32x8 __attribute__((ext_vector_type(8)));

// ---------------- P0: x fp32 -> fp16 ----------------------------------------
__global__ __launch_bounds__(256)
void p0_xconv(const float* __restrict__ x, _Float16* __restrict__ xh, int total4) {
  int i = blockIdx.x * 256 + threadIdx.x;
  if (i >= total4) return;
  float4 v = reinterpret_cast<const float4*>(x)[i];
  _Float16 o[4] = {(_Float16)v.x, (_Float16)v.y, (_Float16)v.z, (_Float16)v.w};
  *reinterpret_cast<uint2*>(&xh[(size_t)i * 4]) = *reinterpret_cast<uint2*>(o);
}

// ---------------- P1: W[h][k][f] -> Wth[h][f][k] fp16 -----------------------
__global__ __launch_bounds__(256)
void p1_wconv(const float* __restrict__ W, _Float16* __restrict__ Wth) {
  int idx = blockIdx.x * 256 + threadIdx.x;   // h*64*256 + f*256 + k
  if (idx >= NH * FO * FI) return;
  int k = idx & (FI - 1);
  int f = (idx >> 8) & (FO - 1);
  int h = idx >> 14;
  Wth[idx] = (_Float16)W[((size_t)h * FI + k) * FO + f];
}

// ---------------- K1: T = x @ W per head, fp16 MFMA -------------------------
__global__ __launch_bounds__(256)
void k1_mfma(const _Float16* __restrict__ xh, const _Float16* __restrict__ Wth,
             _Float16* __restrict__ Th, int N) {
  __shared__ _Float16 Xs[64][264];
  const int h   = blockIdx.y;
  const int bm  = blockIdx.x * 64;
  const int t   = threadIdx.x;
  const int lane = t & 63;
  const int wid  = t >> 6;
  const int wr = wid >> 1, wc = wid & 1;

  #pragma unroll
  for (int r = 0; r < 8; ++r) {
    int i = t + r * 256;
    int row = i >> 5;
    int c8 = (i & 31) * 8;
    int grow = bm + row;
    f16x8 v = {};
    if (grow < N)
      v = *reinterpret_cast<const f16x8*>(&xh[(size_t)grow * FI + c8]);
    *reinterpret_cast<f16x8*>(&Xs[row][c8]) = v;
  }
  __syncthreads();

  const int l31 = lane & 31;
  const int kh  = (lane >> 5) * 8;
  const _Float16* Wcol = Wth + ((size_t)h * FO + wc * 32 + l31) * FI;
  const int arow = wr * 32 + l31;

  f32x16 acc = (f32x16)0.0f;
  #pragma unroll
  for (int kk = 0; kk < 16; ++kk) {
    f16x8 af = *reinterpret_cast<const f16x8*>(&Xs[arow][kk * 16 + kh]);
    f16x8 bf = *reinterpret_cast<const f16x8*>(&Wcol[kk * 16 + kh]);
    acc = __builtin_amdgcn_mfma_f32_32x32x16_f16(af, bf, acc, 0, 0, 0);
  }

  const int cbase = h * FO + wc * 32 + l31;
  #pragma unroll
  for (int reg = 0; reg < 16; ++reg) {
    int rr = (reg & 3) + 8 * (reg >> 2) + 4 * (lane >> 5);
    int grow = bm + wr * 32 + rr;
    if (grow < N) Th[(size_t)grow * FC + cbase] = (_Float16)acc[reg];
  }
}

// ---------------- K2: aw[n,h] = dot(T[n,h*64:], a[h]) -----------------------
__global__ __launch_bounds__(512)
void k2_aw(const _Float16* __restrict__ Th, const float* __restrict__ a,
           float* __restrict__ aw, int N) {
  int n = blockIdx.x;
  int w = threadIdx.x >> 6;
  int lane = threadIdx.x & 63;
  float v = (float)Th[(size_t)n * FC + w * FO + lane] * a[w * FO + lane];
  #pragma unroll
  for (int off = 32; off; off >>= 1) v += __shfl_down(v, off);
  if (lane == 0) aw[n * NH + w] = v;
}

// ---------------- B1: degree histogram --------------------------------------
__global__ __launch_bounds__(256)
void b1_hist(const int* __restrict__ rows, int* __restrict__ deg, int E) {
  int e = blockIdx.x * 256 + threadIdx.x;
  if (e < E) atomicAdd(&deg[rows[e]], 1);
}

// ---------------- B2a: per-block sums (1024 elems/block) --------------------
__global__ __launch_bounds__(256)
void b2a_blocksum(const int* __restrict__ deg, int* __restrict__ blocksums, int N) {
  __shared__ int red[256];
  const int t = threadIdx.x;
  const int base = blockIdx.x * 1024 + t * 4;
  int s = 0;
  #pragma unroll
  for (int j = 0; j < 4; ++j) { int i = base + j; if (i < N) s += deg[i]; }
  red[t] = s;
  __syncthreads();
  for (int off = 128; off; off >>= 1) {
    if (t < off) red[t] += red[t + off];
    __syncthreads();
  }
  if (t == 0) blocksums[blockIdx.x] = red[0];
}

// ---------------- B2b: exclusive scan of block sums (1 wave) ----------------
__global__ __launch_bounds__(64)
void b2b_scanblocks(int* __restrict__ blocksums, int nb,
                    int* __restrict__ row_start, int N, int E) {
  const int lane = threadIdx.x;
  int carry = 0;
  for (int base = 0; base < nb; base += 64) {
    int i = base + lane;
    int v = (i < nb) ? blocksums[i] : 0;
    int inc = v;
    #pragma unroll
    for (int off = 1; off < 64; off <<= 1) {
      int t = __shfl_up(inc, off);
      if (lane >= off) inc += t;
    }
    if (i < nb) blocksums[i] = inc - v + carry;  // exclusive
    carry += __shfl(inc, 63);
  }
  if (lane == 0) row_start[N] = E;
}

// ---------------- B2c: per-block rescan -> row_start, cursor ----------------
__global__ __launch_bounds__(256)
void b2c_rescan(const int* __restrict__ deg, const int* __restrict__ blocksums,
                int* __restrict__ row_start, int* __restrict__ cursor, int N) {
  __shared__ int ts[256];
  const int t = threadIdx.x;
  const int base = blockIdx.x * 1024 + t * 4;
  int v[4]; int s = 0;
  #pragma unroll
  for (int j = 0; j < 4; ++j) { int i = base + j; v[j] = (i < N) ? deg[i] : 0; s += v[j]; }
  ts[t] = s;
  __syncthreads();
  for (int off = 1; off < 256; off <<= 1) {
    int add = (t >= off) ? ts[t - off] : 0;
    __syncthreads();
    ts[t] += add;
    __syncthreads();
  }
  int run = blocksums[blockIdx.x] + ts[t] - s;  // exclusive within grid
  #pragma unroll
  for (int j = 0; j < 4; ++j) {
    int i = base + j;
    if (i < N) { row_start[i] = run; cursor[i] = run; run += v[j]; }
  }
}

// ---------------- B3: scatter cols into CSR order ---------------------------
__global__ __launch_bounds__(256)
void b3_scatter(const int* __restrict__ rows, const int* __restrict__ cols,
                int* __restrict__ cursor, int* __restrict__ colperm, int E) {
  int e = blockIdx.x * 256 + threadIdx.x;
  if (e >= E) return;
  int pos = atomicAdd(&cursor[rows[e]], 1);
  colperm[pos] = cols[e];
}

// ---------------- K4: fused softmax + aggregation + bias + relu -------------
__global__ __launch_bounds__(256)
void k4_fused(const int* __restrict__ row_start, const int* __restrict__ colperm,
              const float* __restrict__ aw, const _Float16* __restrict__ Th,
              const float* __restrict__ b, float* __restrict__ out, int N) {
  const int lane = threadIdx.x & 63;
  const int r = blockIdx.x * 4 + (threadIdx.x >> 6);
  if (r >= N) return;

  const int s0 = row_start[r], s1 = row_start[r + 1];

  f32x8 awr = *reinterpret_cast<const f32x8*>(&aw[(size_t)r * NH]);

  float facc[NH] = {};
  float dacc[NH] = {};

  for (int base = s0; base < s1; base += 64) {
    const int m = min(64, s1 - base);
    const bool valid = lane < m;
    int c_l = valid ? colperm[base + lane] : 0;

    // lane-parallel: ex for this lane's edge (invalid lanes carry 0)
    f32x8 awc = *reinterpret_cast<const f32x8*>(&aw[(size_t)c_l * NH]);
    float ex[NH];
    #pragma unroll
    for (int h = 0; h < NH; ++h) {
      float s = awr[h] + awc[h];
      float lr = s > 0.f ? s : 0.2f * s;
      ex[h] = valid ? __expf(lr) : 0.f;
      dacc[h] += ex[h];
    }

    // serial over edges, 2 at a time (invalid trailing lane contributes 0)
    for (int j = 0; j < m; j += 2) {
      int cj0 = __shfl(c_l, j);
      int cj1 = __shfl(c_l, j + 1);
      const _Float16* tp0 = Th + (size_t)cj0 * FC + lane;
      const _Float16* tp1 = Th + (size_t)cj1 * FC + lane;
      #pragma unroll
      for (int h = 0; h < NH; ++h) {
        float e0 = __shfl(ex[h], j);
        float e1 = __shfl(ex[h], j + 1);
        facc[h] = fmaf(e0, (float)tp0[h * FO], facc[h]);
        facc[h] = fmaf(e1, (float)tp1[h * FO], facc[h]);
      }
    }
  }

  #pragma unroll
  for (int h = 0; h < NH; ++h) {
    #pragma unroll
    for (int off = 1; off < 64; off <<= 1)
      dacc[h] += __shfl_xor(dacc[h], off);
  }

  float sb = 0.f;
  #pragma unroll
  for (int h = 0; h < NH; ++h) sb += b[h * FO + lane];

  float v = 0.f;
  #pragma unroll
  for (int h = 0; h < NH; ++h) {
    float rden = dacc[h] > 0.f ? 1.0f / dacc[h] : 0.f;
    v += facc[h] * rden;
  }
  v = (v + sb) * 0.125f;
  out[(size_t)r * FO + lane] = v > 0.f ? v : 0.f;
}

extern "C" void kernel_launch(void* const* d_in, const int* in_sizes, int n_in,
                              void* d_out, int out_size, void* d_ws, size_t ws_size,
                              hipStream_t stream) {
  const float* x    = (const float*)d_in[0];
  const float* W    = (const float*)d_in[1];
  const float* a    = (const float*)d_in[2];
  const float* b    = (const float*)d_in[3];
  const int*   rows = (const int*)d_in[4];
  const int*   cols = (const int*)d_in[5];
  const int N = in_sizes[0] / FI;
  const int E = in_sizes[4];

  char* p = (char*)d_ws;
  _Float16* Th       = (_Float16*)p;  p += (size_t)N * FC * sizeof(_Float16);
  _Float16* xh       = (_Float16*)p;  p += (size_t)N * FI * sizeof(_Float16);
  _Float16* Wth      = (_Float16*)p;  p += (size_t)NH * FO * FI * sizeof(_Float16);
  float*    aw       = (float*)p;     p += (size_t)N * NH * sizeof(float);
  int*      deg      = (int*)p;       p += (size_t)N * sizeof(int);
  int*      row_start= (int*)p;       p += (size_t)(N + 4) * sizeof(int);
  int*      cursor   = (int*)p;       p += (size_t)N * sizeof(int);
  int*      colperm  = (int*)p;       p += (size_t)E * sizeof(int);
  int*      blocksums= (int*)p;       p += 64 * sizeof(int);
  float*    out = (float*)d_out;

  const int nb = (N + 1023) / 1024;

  // CSR build
  hipMemsetAsync(deg, 0, (size_t)N * sizeof(int), stream);
  b1_hist<<<(E + 255) / 256, 256, 0, stream>>>(rows, deg, E);
  b2a_blocksum<<<nb, 256, 0, stream>>>(deg, blocksums, N);
  b2b_scanblocks<<<1, 64, 0, stream>>>(blocksums, nb, row_start, N, E);
  b2c_rescan<<<nb, 256, 0, stream>>>(deg, blocksums, row_start, cursor, N);
  b3_scatter<<<(E + 255) / 256, 256, 0, stream>>>(rows, cols, cursor, colperm, E);

  // dense feature transform
  int total4 = N * FI / 4;
  p0_xconv<<<(total4 + 255) / 256, 256, 0, stream>>>(x, xh, total4);
  p1_wconv<<<(NH * FO * FI + 255) / 256, 256, 0, stream>>>(W, Wth);
  k1_mfma<<<dim3((N + 63) / 64, NH), 256, 0, stream>>>(xh, Wth, Th, N);
  k2_aw<<<N, 512, 0, stream>>>(Th, a, aw, N);

  // fused edge pipeline
  k4_fused<<<(N + 3) / 4, 256, 0, stream>>>(row_start, colperm, aw, Th, b, out, N);
}